// Round 11
// baseline (217.395 us; speedup 1.0000x reference)
//
#include <hip/hip_runtime.h>
#include <stdint.h>
#include <stddef.h>

// Problem constants (fixed by the reference).
constexpr int N_NODES = 10000;
constexpr int N_EDGES = 320000;
constexpr int DIM_IN  = 128;
constexpr int DIM_H   = 256;
constexpr int DIM_C   = 32;
constexpr int DIM_OUT = 64;
constexpr int DIM_QKV = DIM_C + DIM_C + DIM_H;  // 320 : [q|k|v]
constexpr int DIM_QK  = 2 * DIM_C;              // 64  : [q|k] compact fp32
constexpr int DIM_CAT = 2 * DIM_H;              // 512 : [h|comm]
constexpr float SCALE = 0.17677669529663687f;   // 1/sqrt(32)
constexpr float EXP2SC = 0.2550348612f;         // SCALE * log2(e)
constexpr int MAXD = 192;   // bucket capacity; Binomial(320k,1e-4) max ~66 (28 sigma margin)
constexpr float VSCALE = 64.0f;                 // fp8 v pre-scale (|v|max ~0.5 -> ~32 << 448)
constexpr int PAD2 = 72;    // 64-k LDS row stride (bf16): 144B rows, 16B-aligned (72=8*9)
constexpr int HP   = 264;   // h-tile LDS row stride: 528B rows, 16B-aligned

#if __has_builtin(__builtin_amdgcn_cvt_pk_f32_fp8) && __has_builtin(__builtin_amdgcn_cvt_pk_fp8_f32)
#define V_FP8 1
#else
#define V_FP8 0   // fallback: bf16 v
#endif

// ---------------- workspace layout (4-byte words) ----------------
constexpr size_t alignw(size_t w) { return (w + 15) & ~size_t(15); }
constexpr size_t OFF_DEG   = 0;
constexpr size_t OFF_COL   = alignw(OFF_DEG + N_NODES);                  // [N][MAXD] bucket
constexpr size_t OFF_QK    = alignw(OFF_COL + (size_t)N_NODES * MAXD);   // fp32 [N][64]
constexpr size_t OFF_VT    = alignw(OFF_QK + (size_t)N_NODES * DIM_QK);         // [N][256] fp8/bf16
constexpr size_t OFF_CATBF = alignw(OFF_VT + (size_t)N_NODES * DIM_H / 2);      // [N][512]
constexpr size_t OFF_WINT  = alignw(OFF_CATBF + (size_t)N_NODES * DIM_CAT / 2); // [256][128]
constexpr size_t OFF_WQKVT = alignw(OFF_WINT + (size_t)DIM_H * DIM_IN / 2);     // [320][256]
constexpr size_t OFF_W1T   = alignw(OFF_WQKVT + (size_t)DIM_QKV * DIM_H / 2);   // [256][512]
constexpr size_t OFF_W2T   = alignw(OFF_W1T + (size_t)DIM_H * DIM_CAT / 2);     // [64][256]

typedef __attribute__((ext_vector_type(8))) short short8;
typedef __attribute__((ext_vector_type(4))) float floatx4;
typedef __attribute__((ext_vector_type(2))) float floatx2;

#define MFMA16 __builtin_amdgcn_mfma_f32_16x16x32_bf16

__device__ inline unsigned short f2bf(float f) {
    uint32_t u = __builtin_bit_cast(uint32_t, f);
    uint32_t r = (u + 0x7fffu + ((u >> 16) & 1u)) >> 16;   // RNE
    return (unsigned short)r;
}
__device__ inline float bf2f_lo(uint32_t u) { return __builtin_bit_cast(float, u << 16); }
__device__ inline float bf2f_hi(uint32_t u) { return __builtin_bit_cast(float, u & 0xffff0000u); }

// ---------------- prep_w: WinT/WqkvT transpose + EDGE SCATTER (deg pre-zeroed) --------
// Scatter moved here (from gemm12) so gemm12 is idempotent -> duplicable for bisection.
__global__ void prep_w(const float* __restrict__ W_in,
                       const float* __restrict__ Wq, const float* __restrict__ Wk,
                       const float* __restrict__ Wv,
                       const int* __restrict__ ei,
                       int* __restrict__ deg, int* __restrict__ col,
                       unsigned short* __restrict__ WinT, unsigned short* __restrict__ WqkvT)
{
    const int i0 = blockIdx.x * blockDim.x + threadIdx.x;
    const int stride = gridDim.x * blockDim.x;   // 512*256 = 131,072
    for (int e = i0; e < N_EDGES; e += stride) {             // 2-3 iters
        int src = ei[e];
        int dst = ei[N_EDGES + e];
        int slot = atomicAdd(&deg[src], 1);
        if (slot < MAXD) col[src * MAXD + slot] = dst;
    }
    for (int idx = i0; idx < DIM_IN * DIM_H; idx += stride) {    // W_in[128][256]
        int k = idx >> 8, n = idx & 255;
        WinT[n * DIM_IN + k] = f2bf(W_in[idx]);
    }
    for (int idx = i0; idx < DIM_H * DIM_C; idx += stride) {     // Wq[256][32] -> rows 0..31
        int k = idx >> 5, n = idx & 31;
        WqkvT[n * DIM_H + k] = f2bf(Wq[idx]);
    }
    for (int idx = i0; idx < DIM_H * DIM_C; idx += stride) {     // Wk -> rows 32..63
        int k = idx >> 5, n = idx & 31;
        WqkvT[(DIM_C + n) * DIM_H + k] = f2bf(Wk[idx]);
    }
    for (int idx = i0; idx < DIM_H * DIM_H; idx += stride) {     // Wv[256][256] -> rows 64..319
        int k = idx >> 8, n = idx & 255;
        WqkvT[(2 * DIM_C + n) * DIM_H + k] = f2bf(Wv[idx]);
    }
}

// ---------------- fused GEMM1+GEMM2, BM=32, K-step 64, REG-PREFETCH pipeline ----------
// IDEMPOTENT (scatter removed): writes cat_bf[:,0:256], qk, v_tab, W1T, W2T — all pure.
__global__ __launch_bounds__(256)
void gemm12(const float* __restrict__ x,
            const unsigned short* __restrict__ WinT, const float* __restrict__ b_in,
            const unsigned short* __restrict__ WqkvT,
            const float* __restrict__ bq, const float* __restrict__ bk,
            const float* __restrict__ bv,
            const float* __restrict__ W1, const float* __restrict__ W2,
            unsigned short* __restrict__ cat_bf, float* __restrict__ qk,
            unsigned short* __restrict__ v_tab,
            unsigned short* __restrict__ W1T, unsigned short* __restrict__ W2T)
{
    __shared__ alignas(16) char SMEM[62976];
    short* hS  = (short*)SMEM;                    // 32 x 264 = 16,896 B
    short* As1 = (short*)(SMEM + 16896);          // 32 x 72  =  4,608 B (phase 1)
    short* Bs1 = (short*)(SMEM + 21504);          // 256 x 72 = 36,864 B (phase 1)
    short* Bs2 = (short*)(SMEM + 16896);          // 320 x 72 = 46,080 B (phase 2, overlaps)
    const int tid   = threadIdx.x;
    const int bid   = blockIdx.x;
    const int wave  = tid >> 6;
    const int lane  = tid & 63;
    const int quad  = lane >> 4;
    const int col16 = lane & 15;
    const int sr    = tid >> 3;          // staging row 0..31
    const int sc    = (tid & 7) * 8;     // staging k-chunk (8 bf16 = 16B), 0..56
    const int row0  = bid * 32;
    const int gr_s  = row0 + sr;

    // ---- phase-1 prologue: issue k0=0 tile loads ----
    float4 xa = {}, xb = {};
    if (gr_s < N_NODES) {
        const float4* xp = (const float4*)(x + (size_t)gr_s * DIM_IN + sc);
        xa = xp[0]; xb = xp[1];
    }
    short8 wreg[8];
    #pragma unroll
    for (int p = 0; p < 8; ++p)
        wreg[p] = *(const short8*)(WinT + (size_t)(sr + p * 32) * DIM_IN + sc);

    short8 breg[10];   // phase-2 prefetch registers
    floatx4 acc[2][4] = {};
    #pragma unroll
    for (int k0 = 0; k0 < DIM_IN; k0 += 64) {
        {   // ds_write staged x tile (inline f32->bf16)
            uint4 o;
            o.x = (uint32_t)f2bf(xa.x) | ((uint32_t)f2bf(xa.y) << 16);
            o.y = (uint32_t)f2bf(xa.z) | ((uint32_t)f2bf(xa.w) << 16);
            o.z = (uint32_t)f2bf(xb.x) | ((uint32_t)f2bf(xb.y) << 16);
            o.w = (uint32_t)f2bf(xb.z) | ((uint32_t)f2bf(xb.w) << 16);
            *(uint4*)(As1 + sr * PAD2 + sc) = o;
        }
        #pragma unroll
        for (int p = 0; p < 8; ++p)
            *(short8*)(Bs1 + (sr + p * 32) * PAD2 + sc) = wreg[p];
        if (k0 + 64 < DIM_IN) {
            xa = {}; xb = {};
            if (gr_s < N_NODES) {
                const float4* xp = (const float4*)(x + (size_t)gr_s * DIM_IN + (k0 + 64) + sc);
                xa = xp[0]; xb = xp[1];
            }
            #pragma unroll
            for (int p = 0; p < 8; ++p)
                wreg[p] = *(const short8*)(WinT + (size_t)(sr + p * 32) * DIM_IN + (k0 + 64) + sc);
        } else {
            #pragma unroll
            for (int p = 0; p < 10; ++p)
                breg[p] = *(const short8*)(WqkvT + (size_t)(sr + p * 32) * DIM_H + sc);
        }
        __syncthreads();
        short8 af[2][2], bfr[4][2];
        #pragma unroll
        for (int m = 0; m < 2; ++m)
            #pragma unroll
            for (int kh = 0; kh < 2; ++kh)
                af[m][kh] = *(const short8*)(As1 + (m * 16 + col16) * PAD2 + kh * 32 + quad * 8);
        #pragma unroll
        for (int n = 0; n < 4; ++n)
            #pragma unroll
            for (int kh = 0; kh < 2; ++kh)
                bfr[n][kh] = *(const short8*)(Bs1 + (wave * 64 + n * 16 + col16) * PAD2 + kh * 32 + quad * 8);
        #pragma unroll
        for (int m = 0; m < 2; ++m)
            #pragma unroll
            for (int n = 0; n < 4; ++n)
                #pragma unroll
                for (int kh = 0; kh < 2; ++kh)
                    acc[m][n] = MFMA16(af[m][kh], bfr[n][kh], acc[m][n], 0, 0, 0);
        __syncthreads();
    }
    // epilogue 1: bias -> bf16 -> hS (LDS) + cat_bf[:, 0:256] (global, for w1w2)
    #pragma unroll
    for (int m = 0; m < 2; ++m)
        #pragma unroll
        for (int n = 0; n < 4; ++n) {
            int gc = wave * 64 + n * 16 + col16;
            float bia = b_in[gc];
            #pragma unroll
            for (int r = 0; r < 4; ++r) {
                int lr = m * 16 + quad * 4 + r;
                unsigned short hv = f2bf(acc[m][n][r] + bia);
                hS[lr * HP + gc] = (short)hv;
                if (row0 + lr < N_NODES) cat_bf[(size_t)(row0 + lr) * DIM_CAT + gc] = hv;
            }
        }
    __syncthreads();

    // ---- phase 2: qkv = h @ WqkvT^T + bias  (K=256, 4 k-steps of 64, prefetched) ----
    floatx4 acc2[2][5] = {};
    #pragma unroll
    for (int k0 = 0; k0 < DIM_H; k0 += 64) {
        #pragma unroll
        for (int p = 0; p < 10; ++p)
            *(short8*)(Bs2 + (sr + p * 32) * PAD2 + sc) = breg[p];
        if (k0 + 64 < DIM_H) {
            #pragma unroll
            for (int p = 0; p < 10; ++p)
                breg[p] = *(const short8*)(WqkvT + (size_t)(sr + p * 32) * DIM_H + (k0 + 64) + sc);
        }
        __syncthreads();
        short8 af[2][2], bfr[5][2];
        #pragma unroll
        for (int m = 0; m < 2; ++m)
            #pragma unroll
            for (int kh = 0; kh < 2; ++kh)
                af[m][kh] = *(const short8*)(hS + (m * 16 + col16) * HP + k0 + kh * 32 + quad * 8);
        #pragma unroll
        for (int n = 0; n < 5; ++n)
            #pragma unroll
            for (int kh = 0; kh < 2; ++kh)
                bfr[n][kh] = *(const short8*)(Bs2 + (wave * 80 + n * 16 + col16) * PAD2 + kh * 32 + quad * 8);
        #pragma unroll
        for (int m = 0; m < 2; ++m)
            #pragma unroll
            for (int n = 0; n < 5; ++n)
                #pragma unroll
                for (int kh = 0; kh < 2; ++kh)
                    acc2[m][n] = MFMA16(af[m][kh], bfr[n][kh], acc2[m][n], 0, 0, 0);
        __syncthreads();
    }
    // epilogue 2: split -> qk fp32 [N][64], v fp8/bf16 [N][256]; bias read direct
    #pragma unroll
    for (int m = 0; m < 2; ++m)
        #pragma unroll
        for (int n = 0; n < 5; ++n) {
            int gc = wave * 80 + n * 16 + col16;
            float bia = (gc < DIM_C) ? bq[gc] : (gc < DIM_QK) ? bk[gc - DIM_C] : bv[gc - DIM_QK];
            #pragma unroll
            for (int r = 0; r < 4; ++r) {
                int gr = row0 + m * 16 + quad * 4 + r;
                if (gr >= N_NODES) continue;
                float v = acc2[m][n][r] + bia;
                if (gc < DIM_QK) {
                    qk[(size_t)gr * DIM_QK + gc] = v;
                } else {
#if V_FP8
                    int pk = __builtin_amdgcn_cvt_pk_fp8_f32(v * VSCALE, 0.f, 0, false);
                    ((unsigned char*)v_tab)[(size_t)gr * DIM_H + (gc - DIM_QK)] =
                        (unsigned char)(pk & 0xff);
#else
                    v_tab[(size_t)gr * DIM_H + (gc - DIM_QK)] = f2bf(v);
#endif
                }
            }
        }

    // ---- tail (off critical path): W1T/W2T transpose (idempotent) ----
    {
        const int stride = gridDim.x * 256;              // 80,128
        const int i0 = bid * 256 + tid;
        for (int idx = i0; idx < DIM_CAT * DIM_H; idx += stride) {   // W1[512][256]
            int k = idx >> 8, n = idx & 255;
            W1T[n * DIM_CAT + k] = f2bf(W1[idx]);
        }
        for (int idx = i0; idx < DIM_H * DIM_OUT; idx += stride) {   // W2[256][64]
            int k = idx >> 6, n = idx & 63;
            W2T[n * DIM_H + k] = f2bf(W2[idx]);
        }
    }
}

// ---------------- fused per-row attention: PAIR-GATHER version (R10) ------------------
__global__ __launch_bounds__(256)
void attn_row(const float* __restrict__ qk, const unsigned short* __restrict__ v_tab,
              const int* __restrict__ deg, const int* __restrict__ col,
              unsigned short* __restrict__ cat_bf) {
    __shared__ alignas(16) int dstS[4][MAXD];
    __shared__ float wS[4][MAXD];
    __shared__ float qS[4][DIM_C];
    const int wave = threadIdx.x >> 6;
    const int lane = threadIdx.x & 63;
    const int row = blockIdx.x * 4 + wave;   // grid is exactly N_NODES/4
    int d = deg[row];
    if (d > MAXD) d = MAXD;
    const int* crow = col + (size_t)row * MAXD;

    for (int p = lane; p < d; p += 64) dstS[wave][p] = crow[p];
    if (lane < DIM_C) qS[wave][lane] = qk[(size_t)row * DIM_QK + lane];
    __syncthreads();

    float mysum = 0.f;
    if (d <= 64) {
        int mydst = (lane < d) ? dstS[wave][lane] : -1;
        bool dup = false;
        {
            const int4* ds4 = (const int4*)(&dstS[wave][0]);
            const int lim = (lane < d) ? lane : 0;
            for (int j0 = 0; j0 < lim; j0 += 4) {
                int4 v = ds4[j0 >> 2];
                dup = dup || (v.x == mydst)
                   || (j0 + 1 < lim && v.y == mydst)
                   || (j0 + 2 < lim && v.z == mydst)
                   || (j0 + 3 < lim && v.w == mydst);
            }
        }
        float w = 0.f;
        if (lane < d && !dup) {
            const float4* kp = (const float4*)(qk + (size_t)mydst * DIM_QK + DIM_C);
            float s = 0.f;
            #pragma unroll
            for (int i = 0; i < DIM_C / 4; ++i) {
                float4 b = kp[i];
                s += qS[wave][4 * i + 0] * b.x + qS[wave][4 * i + 1] * b.y
                   + qS[wave][4 * i + 2] * b.z + qS[wave][4 * i + 3] * b.w;
            }
            w = exp2f(s * EXP2SC);
        }
        wS[wave][lane] = w;
        mysum = w;
    } else {
        for (int p = lane; p < d; p += 64) {
            int mydst = dstS[wave][p];
            bool dup = false;
            for (int j = 0; j < p; ++j) dup = dup || (dstS[wave][j] == mydst);
            float w = 0.f;
            if (!dup) {
                const float4* kp = (const float4*)(qk + (size_t)mydst * DIM_QK + DIM_C);
                float s = 0.f;
                #pragma unroll
                for (int i = 0; i < DIM_C / 4; ++i) {
                    float4 b = kp[i];
                    s += qS[wave][4 * i + 0] * b.x + qS[wave][4 * i + 1] * b.y
                       + qS[wave][4 * i + 2] * b.z + qS[wave][4 * i + 3] * b.w;
                }
                w = exp2f(s * EXP2SC);
            }
            wS[wave][p] = w;
            mysum += w;
        }
    }
    #pragma unroll
    for (int off = 32; off; off >>= 1) mysum += __shfl_down(mysum, off, 64);
    float total = __shfl(mysum, 0, 64);
#if V_FP8
    float inv = (d > 0 && total > 0.f) ? 1.0f / (total * VSCALE) : 0.f;
#else
    float inv = (d > 0 && total > 0.f) ? 1.0f / total : 0.f;
#endif
    __syncthreads();

    // pair-gather: half h handles neighbors p0+2t+h; lane covers cols [l32*8, l32*8+8)
    const int half = lane >> 5;
    const int l32  = lane & 31;
    float a8[8] = {};
#if V_FP8
    const uint2* vb2 = (const uint2*)v_tab;          // fp8 row = 32 uint2 (256 B)
    for (int p0 = 0; p0 < d; p0 += 16) {
        int j[8]; float w[8];
        #pragma unroll
        for (int t = 0; t < 8; ++t) {
            int idx = p0 + 2 * t + half;
            bool in = idx < d;
            j[t] = in ? dstS[wave][idx] : 0;         // pad: row 0 (L2-hot), weight 0
            w[t] = in ? wS[wave][idx] : 0.f;
        }
        uint2 r[8];
        #pragma unroll
        for (int t = 0; t < 8; ++t) r[t] = vb2[(size_t)j[t] * 32 + l32];
        #pragma unroll
        for (int t = 0; t < 8; ++t) {
            floatx2 c0 = __builtin_amdgcn_cvt_pk_f32_fp8(r[t].x, false);
            floatx2 c1 = __builtin_amdgcn_cvt_pk_f32_fp8(r[t].x, true);
            floatx2 c2 = __builtin_amdgcn_cvt_pk_f32_fp8(r[t].y, false);
            floatx2 c3 = __builtin_amdgcn_cvt_pk_f32_fp8(r[t].y, true);
            a8[0] += w[t] * c0.x; a8[1] += w[t] * c0.y;
            a8[2] += w[t] * c1.x; a8[3] += w[t] * c1.y;
            a8[4] += w[t] * c2.x; a8[5] += w[t] * c2.y;
            a8[6] += w[t] * c3.x; a8[7] += w[t] * c3.y;
        }
    }
#else
    const uint4* vb2 = (const uint4*)v_tab;          // bf16 row = 32 uint4 (512 B)
    for (int p0 = 0; p0 < d; p0 += 16) {
        int j[8]; float w[8];
        #pragma unroll
        for (int t = 0; t < 8; ++t) {
            int idx = p0 + 2 * t + half;
            bool in = idx < d;
            j[t] = in ? dstS[wave][idx] : 0;
            w[t] = in ? wS[wave][idx] : 0.f;
        }
        uint4 r[8];
        #pragma unroll
        for (int t = 0; t < 8; ++t) r[t] = vb2[(size_t)j[t] * 32 + l32];
        #pragma unroll
        for (int t = 0; t < 8; ++t) {
            a8[0] += w[t] * bf2f_lo(r[t].x); a8[1] += w[t] * bf2f_hi(r[t].x);
            a8[2] += w[t] * bf2f_lo(r[t].y); a8[3] += w[t] * bf2f_hi(r[t].y);
            a8[4] += w[t] * bf2f_lo(r[t].z); a8[5] += w[t] * bf2f_hi(r[t].z);
            a8[6] += w[t] * bf2f_lo(r[t].w); a8[7] += w[t] * bf2f_hi(r[t].w);
        }
    }
#endif
    #pragma unroll
    for (int i = 0; i < 8; ++i) {
        a8[i] += __shfl_xor(a8[i], 32, 64);
        a8[i] *= inv;
    }
    if (half == 0) {
        uint4 o;
        o.x = (uint32_t)f2bf(a8[0]) | ((uint32_t)f2bf(a8[1]) << 16);
        o.y = (uint32_t)f2bf(a8[2]) | ((uint32_t)f2bf(a8[3]) << 16);
        o.z = (uint32_t)f2bf(a8[4]) | ((uint32_t)f2bf(a8[5]) << 16);
        o.w = (uint32_t)f2bf(a8[6]) | ((uint32_t)f2bf(a8[7]) << 16);
        *(uint4*)(cat_bf + (size_t)row * DIM_CAT + DIM_H + l32 * 8) = o;
    }
}

// ---------------- fused W1(relu) + W2 GEMM, BM=32, K-step 64, REG-PREFETCH ------------
__global__ __launch_bounds__(256)
void gemm_w1w2(const unsigned short* __restrict__ cat, const unsigned short* __restrict__ W1T,
               const float* __restrict__ b1, const unsigned short* __restrict__ W2T,
               const float* __restrict__ b2, float* __restrict__ out, int M)
{
    constexpr int TP = 260;   // Ts row stride (bf16)
    __shared__ short As[32 * PAD2];                //  4,608 B
    __shared__ short BsTs[256 * PAD2];             // 36,864 B: Bs; Ts (32*260*2=16,640) aliases
    short* Bs = BsTs;
    short* Ts = BsTs;
    const int tid   = threadIdx.x;
    const int wave  = tid >> 6;
    const int lane  = tid & 63;
    const int quad  = lane >> 4;
    const int col16 = lane & 15;
    const int row0  = blockIdx.x * 32;

    const int sr = tid >> 3;          // 0..31
    const int sc = (tid & 7) * 8;     // 16B k-chunk, 0..56
    const int gr_s = row0 + sr;

    // prologue: issue k0=0 tile loads
    short8 areg = {};
    if (gr_s < M) areg = *(const short8*)(cat + (size_t)gr_s * DIM_CAT + sc);
    short8 breg[8];
    #pragma unroll
    for (int p = 0; p < 8; ++p)
        breg[p] = *(const short8*)(W1T + (size_t)(sr + p * 32) * DIM_CAT + sc);

    // ---- phase A: z = relu(cat @ W1T^T + b1), 32 rows x 256 cols, K=512 (8 steps) ----
    floatx4 acc[2][4] = {};
    #pragma unroll
    for (int k0 = 0; k0 < DIM_CAT; k0 += 64) {
        *(short8*)(As + sr * PAD2 + sc) = areg;
        #pragma unroll
        for (int p = 0; p < 8; ++p)
            *(short8*)(Bs + (sr + p * 32) * PAD2 + sc) = breg[p];
        if (k0 + 64 < DIM_CAT) {   // prefetch next tile (hidden under MFMA below)
            areg = short8{};
            if (gr_s < M) areg = *(const short8*)(cat + (size_t)gr_s * DIM_CAT + (k0 + 64) + sc);
            #pragma unroll
            for (int p = 0; p < 8; ++p)
                breg[p] = *(const short8*)(W1T + (size_t)(sr + p * 32) * DIM_CAT + (k0 + 64) + sc);
        }
        __syncthreads();
        short8 af[2][2], bfr[4][2];
        #pragma unroll
        for (int m = 0; m < 2; ++m)
            #pragma unroll
            for (int kh = 0; kh < 2; ++kh)
                af[m][kh] = *(const short8*)(As + (m * 16 + col16) * PAD2 + kh * 32 + quad * 8);
        #pragma unroll
        for (int n = 0; n < 4; ++n)
            #pragma unroll
            for (int kh = 0; kh < 2; ++kh)
                bfr[n][kh] = *(const short8*)(Bs + (wave * 64 + n * 16 + col16) * PAD2 + kh * 32 + quad * 8);
        #pragma unroll
        for (int m = 0; m < 2; ++m)
            #pragma unroll
            for (int n = 0; n < 4; ++n)
                #pragma unroll
                for (int kh = 0; kh < 2; ++kh)
                    acc[m][n] = MFMA16(af[m][kh], bfr[n][kh], acc[m][n], 0, 0, 0);
        __syncthreads();   // Bs reads done before next staging / Ts overwrite
    }

    // epilogue A: bias + relu -> bf16 z tile in Ts (aliases Bs; safe after final barrier)
    #pragma unroll
    for (int m = 0; m < 2; ++m)
        #pragma unroll
        for (int n = 0; n < 4; ++n) {
            int gc = wave * 64 + n * 16 + col16;
            float bia = b1[gc];
            #pragma unroll
            for (int r = 0; r < 4; ++r) {
                int lr = m * 16 + quad * 4 + r;
                Ts[lr * TP + gc] = (short)f2bf(fmaxf(acc[m][n][r] + bia, 0.f));
            }
        }
    __syncthreads();

    // ---- phase B: out = z @ W2T^T + b2, K=256; wave owns cols [wave*16, wave*16+16) ----
    floatx4 acc2[2] = {};
    #pragma unroll
    for (int k0 = 0; k0 < DIM_H; k0 += 32) {
        short8 b = *(const short8*)(W2T + (size_t)(wave * 16 + col16) * DIM_H + k0 + quad * 8);
        #pragma unroll
        for (int m = 0; m < 2; ++m) {
            short8 a = *(const short8*)(Ts + (m * 16 + col16) * TP + k0 + quad * 8);
            acc2[m] = MFMA16(a, b, acc2[m], 0, 0, 0);
        }
    }
    #pragma unroll
    for (int m = 0; m < 2; ++m) {
        int gc = wave * 16 + col16;
        float bia = b2[gc];
        #pragma unroll
        for (int r = 0; r < 4; ++r) {
            int gr = row0 + m * 16 + quad * 4 + r;
            if (gr < M) out[(size_t)gr * DIM_OUT + gc] = acc2[m][r] + bia;
        }
    }
}

// ---------------- launcher: gemm12 x4 (bisection #3), singles otherwise --------------
extern "C" void kernel_launch(void* const* d_in, const int* in_sizes, int n_in,
                              void* d_out, int out_size, void* d_ws, size_t ws_size,
                              hipStream_t stream) {
    (void)in_sizes; (void)n_in; (void)out_size; (void)ws_size;
    const float* x    = (const float*)d_in[0];
    const int*   ei   = (const int*)d_in[1];
    const float* W_in = (const float*)d_in[2];
    const float* b_in = (const float*)d_in[3];
    const float* Wq   = (const float*)d_in[4];
    const float* bq   = (const float*)d_in[5];
    const float* Wk   = (const float*)d_in[6];
    const float* bk   = (const float*)d_in[7];
    const float* Wv   = (const float*)d_in[8];
    const float* bv   = (const float*)d_in[9];
    const float* W1   = (const float*)d_in[10];
    const float* b1   = (const float*)d_in[11];
    const float* W2   = (const float*)d_in[12];
    const float* b2   = (const float*)d_in[13];
    float* out = (float*)d_out;

    uint32_t* ws      = (uint32_t*)d_ws;
    int*      deg     = (int*)(ws + OFF_DEG);
    int*      col     = (int*)(ws + OFF_COL);
    float*    qk      = (float*)(ws + OFF_QK);
    unsigned short* v_tab  = (unsigned short*)(ws + OFF_VT);
    unsigned short* cat_bf = (unsigned short*)(ws + OFF_CATBF);
    unsigned short* WinT   = (unsigned short*)(ws + OFF_WINT);
    unsigned short* WqkvT  = (unsigned short*)(ws + OFF_WQKVT);
    unsigned short* W1T    = (unsigned short*)(ws + OFF_W1T);
    unsigned short* W2T    = (unsigned short*)(ws + OFF_W2T);

    // 0) zero deg (scatter moved into prep_w, needs clean counters)
    hipMemsetAsync(deg, 0, N_NODES * sizeof(int), stream);
    // 1) prep: WinT/WqkvT transpose + edge bucket-scatter
    prep_w<<<512, 256, 0, stream>>>(W_in, Wq, Wk, Wv, ei, deg, col, WinT, WqkvT);
    // 2) gemm12 — LAUNCHED 4x (3 idempotent duplicates). MEASUREMENT:
    //    g12 = (dur - 157)/3 ; prep' ~= 70 - g12.
    gemm12<<<(N_NODES + 31) / 32, 256, 0, stream>>>(
        x, WinT, b_in, WqkvT, bq, bk, bv, W1, W2, cat_bf, qk, v_tab, W1T, W2T);
    gemm12<<<(N_NODES + 31) / 32, 256, 0, stream>>>(
        x, WinT, b_in, WqkvT, bq, bk, bv, W1, W2, cat_bf, qk, v_tab, W1T, W2T);
    gemm12<<<(N_NODES + 31) / 32, 256, 0, stream>>>(
        x, WinT, b_in, WqkvT, bq, bk, bv, W1, W2, cat_bf, qk, v_tab, W1T, W2T);
    gemm12<<<(N_NODES + 31) / 32, 256, 0, stream>>>(
        x, WinT, b_in, WqkvT, bq, bk, bv, W1, W2, cat_bf, qk, v_tab, W1T, W2T);
    // 3) fused sparse attention (pair-gather, exp2) — single
    attn_row<<<N_NODES / 4, 256, 0, stream>>>(qk, v_tab, deg, col, cat_bf);
    // 4) w1w2 — single
    gemm_w1w2<<<(N_NODES + 31) / 32, 256, 0, stream>>>(
        cat_bf, W1T, b1, W2T, b2, out, N_NODES);
}

// Round 12
// 193.902 us; speedup vs baseline: 1.1212x; 1.1212x over previous
//
#include <hip/hip_runtime.h>
#include <stdint.h>
#include <stddef.h>

// Problem constants (fixed by the reference).
constexpr int N_NODES = 10000;
constexpr int N_EDGES = 320000;
constexpr int DIM_IN  = 128;
constexpr int DIM_H   = 256;
constexpr int DIM_C   = 32;
constexpr int DIM_OUT = 64;
constexpr int DIM_QKV = DIM_C + DIM_C + DIM_H;  // 320 : [q|k|v]
constexpr int DIM_QK  = 2 * DIM_C;              // 64  : [q|k] compact fp32
constexpr int DIM_CAT = 2 * DIM_H;              // 512 : [h|comm]
constexpr float SCALE = 0.17677669529663687f;   // 1/sqrt(32)
constexpr float EXP2SC = 0.2550348612f;         // SCALE * log2(e)
constexpr int MAXD = 192;   // bucket capacity; Binomial(320k,1e-4) max ~66 (28 sigma margin)
constexpr float VSCALE = 64.0f;                 // fp8 v pre-scale (|v|max ~0.5 -> ~32 << 448)
constexpr int PAD2 = 72;    // 64-k LDS row stride (bf16): 144B rows, 16B-aligned (72=8*9)
constexpr int HP   = 264;   // h-tile LDS row stride: 528B rows, 16B-aligned

#if __has_builtin(__builtin_amdgcn_cvt_pk_f32_fp8) && __has_builtin(__builtin_amdgcn_cvt_pk_fp8_f32)
#define V_FP8 1
#else
#define V_FP8 0   // fallback: bf16 v
#endif

// ---------------- workspace layout (4-byte words) ----------------
constexpr size_t alignw(size_t w) { return (w + 15) & ~size_t(15); }
constexpr size_t OFF_DEG   = 0;
constexpr size_t OFF_COL   = alignw(OFF_DEG + N_NODES);                  // [N][MAXD] bucket
constexpr size_t OFF_QK    = alignw(OFF_COL + (size_t)N_NODES * MAXD);   // fp32 [N][64]
constexpr size_t OFF_VT    = alignw(OFF_QK + (size_t)N_NODES * DIM_QK);         // [N][256] fp8/bf16
constexpr size_t OFF_CATBF = alignw(OFF_VT + (size_t)N_NODES * DIM_H / 2);      // [N][512] (h half used)
constexpr size_t OFF_WINT  = alignw(OFF_CATBF + (size_t)N_NODES * DIM_CAT / 2); // [256][128]
constexpr size_t OFF_WQKVT = alignw(OFF_WINT + (size_t)DIM_H * DIM_IN / 2);     // [320][256]
constexpr size_t OFF_W1T   = alignw(OFF_WQKVT + (size_t)DIM_QKV * DIM_H / 2);   // [256][512]
constexpr size_t OFF_W2T   = alignw(OFF_W1T + (size_t)DIM_H * DIM_CAT / 2);     // [64][256]

typedef __attribute__((ext_vector_type(8))) short short8;
typedef __attribute__((ext_vector_type(4))) float floatx4;
typedef __attribute__((ext_vector_type(2))) float floatx2;

#define MFMA16 __builtin_amdgcn_mfma_f32_16x16x32_bf16

__device__ inline unsigned short f2bf(float f) {
    uint32_t u = __builtin_bit_cast(uint32_t, f);
    uint32_t r = (u + 0x7fffu + ((u >> 16) & 1u)) >> 16;   // RNE
    return (unsigned short)r;
}
__device__ inline float bf2f_lo(uint32_t u) { return __builtin_bit_cast(float, u << 16); }
__device__ inline float bf2f_hi(uint32_t u) { return __builtin_bit_cast(float, u & 0xffff0000u); }

// ---------------- prep_w: WinT/WqkvT transpose + edge scatter (deg pre-zeroed) --------
__global__ void prep_w(const float* __restrict__ W_in,
                       const float* __restrict__ Wq, const float* __restrict__ Wk,
                       const float* __restrict__ Wv,
                       const int* __restrict__ ei,
                       int* __restrict__ deg, int* __restrict__ col,
                       unsigned short* __restrict__ WinT, unsigned short* __restrict__ WqkvT)
{
    const int i0 = blockIdx.x * blockDim.x + threadIdx.x;
    const int stride = gridDim.x * blockDim.x;   // 131,072
    for (int e = i0; e < N_EDGES; e += stride) {
        int src = ei[e];
        int dst = ei[N_EDGES + e];
        int slot = atomicAdd(&deg[src], 1);
        if (slot < MAXD) col[src * MAXD + slot] = dst;
    }
    for (int idx = i0; idx < DIM_IN * DIM_H; idx += stride) {    // W_in[128][256]
        int k = idx >> 8, n = idx & 255;
        WinT[n * DIM_IN + k] = f2bf(W_in[idx]);
    }
    for (int idx = i0; idx < DIM_H * DIM_C; idx += stride) {     // Wq[256][32] -> rows 0..31
        int k = idx >> 5, n = idx & 31;
        WqkvT[n * DIM_H + k] = f2bf(Wq[idx]);
    }
    for (int idx = i0; idx < DIM_H * DIM_C; idx += stride) {     // Wk -> rows 32..63
        int k = idx >> 5, n = idx & 31;
        WqkvT[(DIM_C + n) * DIM_H + k] = f2bf(Wk[idx]);
    }
    for (int idx = i0; idx < DIM_H * DIM_H; idx += stride) {     // Wv[256][256] -> rows 64..319
        int k = idx >> 8, n = idx & 255;
        WqkvT[(2 * DIM_C + n) * DIM_H + k] = f2bf(Wv[idx]);
    }
}

// ---------------- fused GEMM1+GEMM2, BM=32, K-step 64, REG-PREFETCH (R11-proven) ------
__global__ __launch_bounds__(256)
void gemm12(const float* __restrict__ x,
            const unsigned short* __restrict__ WinT, const float* __restrict__ b_in,
            const unsigned short* __restrict__ WqkvT,
            const float* __restrict__ bq, const float* __restrict__ bk,
            const float* __restrict__ bv,
            const float* __restrict__ W1, const float* __restrict__ W2,
            unsigned short* __restrict__ cat_bf, float* __restrict__ qk,
            unsigned short* __restrict__ v_tab,
            unsigned short* __restrict__ W1T, unsigned short* __restrict__ W2T)
{
    __shared__ alignas(16) char SMEM[62976];
    short* hS  = (short*)SMEM;                    // 32 x 264 = 16,896 B
    short* As1 = (short*)(SMEM + 16896);          // 32 x 72  =  4,608 B (phase 1)
    short* Bs1 = (short*)(SMEM + 21504);          // 256 x 72 = 36,864 B (phase 1)
    short* Bs2 = (short*)(SMEM + 16896);          // 320 x 72 = 46,080 B (phase 2, overlaps)
    const int tid   = threadIdx.x;
    const int bid   = blockIdx.x;
    const int wave  = tid >> 6;
    const int lane  = tid & 63;
    const int quad  = lane >> 4;
    const int col16 = lane & 15;
    const int sr    = tid >> 3;          // staging row 0..31
    const int sc    = (tid & 7) * 8;     // staging k-chunk (8 bf16 = 16B), 0..56
    const int row0  = bid * 32;
    const int gr_s  = row0 + sr;

    float4 xa = {}, xb = {};
    if (gr_s < N_NODES) {
        const float4* xp = (const float4*)(x + (size_t)gr_s * DIM_IN + sc);
        xa = xp[0]; xb = xp[1];
    }
    short8 wreg[8];
    #pragma unroll
    for (int p = 0; p < 8; ++p)
        wreg[p] = *(const short8*)(WinT + (size_t)(sr + p * 32) * DIM_IN + sc);

    short8 breg[10];
    floatx4 acc[2][4] = {};
    #pragma unroll
    for (int k0 = 0; k0 < DIM_IN; k0 += 64) {
        {   // ds_write staged x tile (inline f32->bf16)
            uint4 o;
            o.x = (uint32_t)f2bf(xa.x) | ((uint32_t)f2bf(xa.y) << 16);
            o.y = (uint32_t)f2bf(xa.z) | ((uint32_t)f2bf(xa.w) << 16);
            o.z = (uint32_t)f2bf(xb.x) | ((uint32_t)f2bf(xb.y) << 16);
            o.w = (uint32_t)f2bf(xb.z) | ((uint32_t)f2bf(xb.w) << 16);
            *(uint4*)(As1 + sr * PAD2 + sc) = o;
        }
        #pragma unroll
        for (int p = 0; p < 8; ++p)
            *(short8*)(Bs1 + (sr + p * 32) * PAD2 + sc) = wreg[p];
        if (k0 + 64 < DIM_IN) {
            xa = {}; xb = {};
            if (gr_s < N_NODES) {
                const float4* xp = (const float4*)(x + (size_t)gr_s * DIM_IN + (k0 + 64) + sc);
                xa = xp[0]; xb = xp[1];
            }
            #pragma unroll
            for (int p = 0; p < 8; ++p)
                wreg[p] = *(const short8*)(WinT + (size_t)(sr + p * 32) * DIM_IN + (k0 + 64) + sc);
        } else {
            #pragma unroll
            for (int p = 0; p < 10; ++p)
                breg[p] = *(const short8*)(WqkvT + (size_t)(sr + p * 32) * DIM_H + sc);
        }
        __syncthreads();
        short8 af[2][2], bfr[4][2];
        #pragma unroll
        for (int m = 0; m < 2; ++m)
            #pragma unroll
            for (int kh = 0; kh < 2; ++kh)
                af[m][kh] = *(const short8*)(As1 + (m * 16 + col16) * PAD2 + kh * 32 + quad * 8);
        #pragma unroll
        for (int n = 0; n < 4; ++n)
            #pragma unroll
            for (int kh = 0; kh < 2; ++kh)
                bfr[n][kh] = *(const short8*)(Bs1 + (wave * 64 + n * 16 + col16) * PAD2 + kh * 32 + quad * 8);
        #pragma unroll
        for (int m = 0; m < 2; ++m)
            #pragma unroll
            for (int n = 0; n < 4; ++n)
                #pragma unroll
                for (int kh = 0; kh < 2; ++kh)
                    acc[m][n] = MFMA16(af[m][kh], bfr[n][kh], acc[m][n], 0, 0, 0);
        __syncthreads();
    }
    // epilogue 1: bias -> bf16 -> hS (LDS) + cat_bf[:, 0:256]
    #pragma unroll
    for (int m = 0; m < 2; ++m)
        #pragma unroll
        for (int n = 0; n < 4; ++n) {
            int gc = wave * 64 + n * 16 + col16;
            float bia = b_in[gc];
            #pragma unroll
            for (int r = 0; r < 4; ++r) {
                int lr = m * 16 + quad * 4 + r;
                unsigned short hv = f2bf(acc[m][n][r] + bia);
                hS[lr * HP + gc] = (short)hv;
                if (row0 + lr < N_NODES) cat_bf[(size_t)(row0 + lr) * DIM_CAT + gc] = hv;
            }
        }
    __syncthreads();

    // ---- phase 2: qkv = h @ WqkvT^T + bias ----
    floatx4 acc2[2][5] = {};
    #pragma unroll
    for (int k0 = 0; k0 < DIM_H; k0 += 64) {
        #pragma unroll
        for (int p = 0; p < 10; ++p)
            *(short8*)(Bs2 + (sr + p * 32) * PAD2 + sc) = breg[p];
        if (k0 + 64 < DIM_H) {
            #pragma unroll
            for (int p = 0; p < 10; ++p)
                breg[p] = *(const short8*)(WqkvT + (size_t)(sr + p * 32) * DIM_H + (k0 + 64) + sc);
        }
        __syncthreads();
        short8 af[2][2], bfr[5][2];
        #pragma unroll
        for (int m = 0; m < 2; ++m)
            #pragma unroll
            for (int kh = 0; kh < 2; ++kh)
                af[m][kh] = *(const short8*)(hS + (m * 16 + col16) * HP + k0 + kh * 32 + quad * 8);
        #pragma unroll
        for (int n = 0; n < 5; ++n)
            #pragma unroll
            for (int kh = 0; kh < 2; ++kh)
                bfr[n][kh] = *(const short8*)(Bs2 + (wave * 80 + n * 16 + col16) * PAD2 + kh * 32 + quad * 8);
        #pragma unroll
        for (int m = 0; m < 2; ++m)
            #pragma unroll
            for (int n = 0; n < 5; ++n)
                #pragma unroll
                for (int kh = 0; kh < 2; ++kh)
                    acc2[m][n] = MFMA16(af[m][kh], bfr[n][kh], acc2[m][n], 0, 0, 0);
        __syncthreads();
    }
    // epilogue 2: split -> qk fp32 [N][64], v fp8/bf16 [N][256]
    #pragma unroll
    for (int m = 0; m < 2; ++m)
        #pragma unroll
        for (int n = 0; n < 5; ++n) {
            int gc = wave * 80 + n * 16 + col16;
            float bia = (gc < DIM_C) ? bq[gc] : (gc < DIM_QK) ? bk[gc - DIM_C] : bv[gc - DIM_QK];
            #pragma unroll
            for (int r = 0; r < 4; ++r) {
                int gr = row0 + m * 16 + quad * 4 + r;
                if (gr >= N_NODES) continue;
                float v = acc2[m][n][r] + bia;
                if (gc < DIM_QK) {
                    qk[(size_t)gr * DIM_QK + gc] = v;
                } else {
#if V_FP8
                    int pk = __builtin_amdgcn_cvt_pk_fp8_f32(v * VSCALE, 0.f, 0, false);
                    ((unsigned char*)v_tab)[(size_t)gr * DIM_H + (gc - DIM_QK)] =
                        (unsigned char)(pk & 0xff);
#else
                    v_tab[(size_t)gr * DIM_H + (gc - DIM_QK)] = f2bf(v);
#endif
                }
            }
        }

    // ---- tail: W1T/W2T transpose (consumed by attn_w1w2) ----
    {
        const int stride = gridDim.x * 256;              // 80,128
        const int i0 = bid * 256 + tid;
        for (int idx = i0; idx < DIM_CAT * DIM_H; idx += stride) {   // W1[512][256]
            int k = idx >> 8, n = idx & 255;
            W1T[n * DIM_CAT + k] = f2bf(W1[idx]);
        }
        for (int idx = i0; idx < DIM_H * DIM_OUT; idx += stride) {   // W2[256][64]
            int k = idx >> 6, n = idx & 63;
            W2T[n * DIM_H + k] = f2bf(W2[idx]);
        }
    }
}

// ================== MERGED attn + w1w2: one block per 32-row strip ====================
// Phase A: 4 waves x 8 rows of pair-gather attention (R10 algorithm) -> comm in LDS.
// Phase B: out = relu([h|comm] @ W1T^T + b1) @ W2T^T + b2 with comm read from LDS.
// comm NEVER touches global memory. Heterogeneous blocks (attn VALU vs GEMM MFMA)
// overlap across CUs. LDS 58,368 B: commS[32][264] | union(attn scratch; As+BsTs).
__global__ __launch_bounds__(256)
void attn_w1w2(const float* __restrict__ qk, const unsigned short* __restrict__ v_tab,
               const int* __restrict__ deg, const int* __restrict__ col,
               const unsigned short* __restrict__ cat_bf,
               const unsigned short* __restrict__ W1T, const float* __restrict__ b1,
               const unsigned short* __restrict__ W2T, const float* __restrict__ b2,
               float* __restrict__ out, int M)
{
    constexpr int CP = 264;   // commS row stride (bf16), same banking as HP (proven)
    constexpr int TP = 260;   // Ts row stride (bf16)
    __shared__ alignas(16) char SMEM[58368];
    short* commS = (short*)SMEM;                         // 32 x 264 = 16,896 B (persistent)
    int*   dstS  = (int*)(SMEM + 16896);                 // [4][192] = 3,072 B (phase A)
    float* wS    = (float*)(SMEM + 16896 + 3072);        // [4][192] = 3,072 B (phase A)
    float* qS    = (float*)(SMEM + 16896 + 6144);        // [4][32]  =   512 B (phase A)
    short* As    = (short*)(SMEM + 16896);               // 32 x 72 (phase B, aliases scratch)
    short* BsTs  = (short*)(SMEM + 21504);               // 256 x 72 = 36,864 B (phase B)
    short* Bs = BsTs;
    short* Ts = BsTs;
    const int tid   = threadIdx.x;
    const int wave  = tid >> 6;
    const int lane  = tid & 63;
    const int quad  = lane >> 4;
    const int col16 = lane & 15;
    const int row0  = blockIdx.x * 32;

    // ---------------- phase A: attention for rows row0..row0+31 ----------------
    int*   dstW = dstS + wave * MAXD;
    float* wW   = wS   + wave * MAXD;
    float* qW   = qS   + wave * DIM_C;
    const int half = lane >> 5;
    const int l32  = lane & 31;
    #pragma unroll 1
    for (int r8 = 0; r8 < 8; ++r8) {
        const int row = row0 + wave * 8 + r8;
        const bool rowok = row < N_NODES;
        int d = rowok ? deg[row] : 0;
        if (d > MAXD) d = MAXD;
        const int* crow = col + (size_t)row * MAXD;

        for (int p = lane; p < d; p += 64) dstW[p] = crow[p];
        if (rowok && lane < DIM_C) qW[lane] = qk[(size_t)row * DIM_QK + lane];
        __syncthreads();   // uniform: fixed 8-iteration loop, guards on memory only

        float mysum = 0.f;
        if (d <= 64) {
            int mydst = (lane < d) ? dstW[lane] : -1;
            bool dup = false;
            {
                const int4* ds4 = (const int4*)dstW;
                const int lim = (lane < d) ? lane : 0;
                for (int j0 = 0; j0 < lim; j0 += 4) {
                    int4 v = ds4[j0 >> 2];
                    dup = dup || (v.x == mydst)
                       || (j0 + 1 < lim && v.y == mydst)
                       || (j0 + 2 < lim && v.z == mydst)
                       || (j0 + 3 < lim && v.w == mydst);
                }
            }
            float w = 0.f;
            if (lane < d && !dup) {
                const float4* kp = (const float4*)(qk + (size_t)mydst * DIM_QK + DIM_C);
                float s = 0.f;
                #pragma unroll
                for (int i = 0; i < DIM_C / 4; ++i) {
                    float4 b = kp[i];
                    s += qW[4 * i + 0] * b.x + qW[4 * i + 1] * b.y
                       + qW[4 * i + 2] * b.z + qW[4 * i + 3] * b.w;
                }
                w = exp2f(s * EXP2SC);
            }
            wW[lane] = w;
            mysum = w;
        } else {
            for (int p = lane; p < d; p += 64) {
                int mydst = dstW[p];
                bool dup = false;
                for (int j = 0; j < p; ++j) dup = dup || (dstW[j] == mydst);
                float w = 0.f;
                if (!dup) {
                    const float4* kp = (const float4*)(qk + (size_t)mydst * DIM_QK + DIM_C);
                    float s = 0.f;
                    #pragma unroll
                    for (int i = 0; i < DIM_C / 4; ++i) {
                        float4 b = kp[i];
                        s += qW[4 * i + 0] * b.x + qW[4 * i + 1] * b.y
                           + qW[4 * i + 2] * b.z + qW[4 * i + 3] * b.w;
                    }
                    w = exp2f(s * EXP2SC);
                }
                wW[p] = w;
                mysum += w;
            }
        }
        #pragma unroll
        for (int off = 32; off; off >>= 1) mysum += __shfl_down(mysum, off, 64);
        float total = __shfl(mysum, 0, 64);
#if V_FP8
        float inv = (d > 0 && total > 0.f) ? 1.0f / (total * VSCALE) : 0.f;
#else
        float inv = (d > 0 && total > 0.f) ? 1.0f / total : 0.f;
#endif

        float a8[8] = {};
#if V_FP8
        const uint2* vb2 = (const uint2*)v_tab;          // fp8 row = 32 uint2 (256 B)
        for (int p0 = 0; p0 < d; p0 += 16) {
            int j[8]; float w[8];
            #pragma unroll
            for (int t = 0; t < 8; ++t) {
                int idx = p0 + 2 * t + half;
                bool in = idx < d;
                j[t] = in ? dstW[idx] : 0;
                w[t] = in ? wW[idx] : 0.f;
            }
            uint2 r[8];
            #pragma unroll
            for (int t = 0; t < 8; ++t) r[t] = vb2[(size_t)j[t] * 32 + l32];
            #pragma unroll
            for (int t = 0; t < 8; ++t) {
                floatx2 c0 = __builtin_amdgcn_cvt_pk_f32_fp8(r[t].x, false);
                floatx2 c1 = __builtin_amdgcn_cvt_pk_f32_fp8(r[t].x, true);
                floatx2 c2 = __builtin_amdgcn_cvt_pk_f32_fp8(r[t].y, false);
                floatx2 c3 = __builtin_amdgcn_cvt_pk_f32_fp8(r[t].y, true);
                a8[0] += w[t] * c0.x; a8[1] += w[t] * c0.y;
                a8[2] += w[t] * c1.x; a8[3] += w[t] * c1.y;
                a8[4] += w[t] * c2.x; a8[5] += w[t] * c2.y;
                a8[6] += w[t] * c3.x; a8[7] += w[t] * c3.y;
            }
        }
#else
        const uint4* vb2 = (const uint4*)v_tab;          // bf16 row = 32 uint4 (512 B)
        for (int p0 = 0; p0 < d; p0 += 16) {
            int j[8]; float w[8];
            #pragma unroll
            for (int t = 0; t < 8; ++t) {
                int idx = p0 + 2 * t + half;
                bool in = idx < d;
                j[t] = in ? dstW[idx] : 0;
                w[t] = in ? wW[idx] : 0.f;
            }
            uint4 r[8];
            #pragma unroll
            for (int t = 0; t < 8; ++t) r[t] = vb2[(size_t)j[t] * 32 + l32];
            #pragma unroll
            for (int t = 0; t < 8; ++t) {
                a8[0] += w[t] * bf2f_lo(r[t].x); a8[1] += w[t] * bf2f_hi(r[t].x);
                a8[2] += w[t] * bf2f_lo(r[t].y); a8[3] += w[t] * bf2f_hi(r[t].y);
                a8[4] += w[t] * bf2f_lo(r[t].z); a8[5] += w[t] * bf2f_hi(r[t].z);
                a8[6] += w[t] * bf2f_lo(r[t].w); a8[7] += w[t] * bf2f_hi(r[t].w);
            }
        }
#endif
        #pragma unroll
        for (int i = 0; i < 8; ++i) {
            a8[i] += __shfl_xor(a8[i], 32, 64);
            a8[i] *= inv;
        }
        if (half == 0) {   // comm -> LDS only (never global)
            uint4 o;
            o.x = (uint32_t)f2bf(a8[0]) | ((uint32_t)f2bf(a8[1]) << 16);
            o.y = (uint32_t)f2bf(a8[2]) | ((uint32_t)f2bf(a8[3]) << 16);
            o.z = (uint32_t)f2bf(a8[4]) | ((uint32_t)f2bf(a8[5]) << 16);
            o.w = (uint32_t)f2bf(a8[6]) | ((uint32_t)f2bf(a8[7]) << 16);
            *(uint4*)(commS + (wave * 8 + r8) * CP + l32 * 8) = o;
        }
        __syncthreads();   // uniform; also fences commS/scratch before next row / phase B
    }

    // ---------------- phase B: out = relu([h|comm]@W1T^T + b1) @ W2T^T + b2 ----------
    const int sr = tid >> 3;          // 0..31
    const int sc = (tid & 7) * 8;     // 16B k-chunk, 0..56
    const int gr_s = row0 + sr;

    // prologue: step-0 loads (A = h from cat_bf; B = W1T)
    short8 areg = {};
    if (gr_s < M) areg = *(const short8*)(cat_bf + (size_t)gr_s * DIM_CAT + sc);
    short8 breg[8];
    #pragma unroll
    for (int p = 0; p < 8; ++p)
        breg[p] = *(const short8*)(W1T + (size_t)(sr + p * 32) * DIM_CAT + sc);

    floatx4 acc[2][4] = {};
    #pragma unroll
    for (int ks = 0; ks < 8; ++ks) {
        const int k0 = ks * 64;
        if (ks < 4)   // A tile from global h; comm steps read commS directly
            *(short8*)(As + sr * PAD2 + sc) = areg;
        #pragma unroll
        for (int p = 0; p < 8; ++p)
            *(short8*)(Bs + (sr + p * 32) * PAD2 + sc) = breg[p];
        if (ks < 3) {   // prefetch next h tile
            areg = short8{};
            if (gr_s < M) areg = *(const short8*)(cat_bf + (size_t)gr_s * DIM_CAT + (k0 + 64) + sc);
        }
        if (ks < 7) {   // prefetch next W1T tile
            #pragma unroll
            for (int p = 0; p < 8; ++p)
                breg[p] = *(const short8*)(W1T + (size_t)(sr + p * 32) * DIM_CAT + (k0 + 64) + sc);
        }
        __syncthreads();
        short8 af[2][2], bfr[4][2];
        #pragma unroll
        for (int m = 0; m < 2; ++m)
            #pragma unroll
            for (int kh = 0; kh < 2; ++kh)
                af[m][kh] = (ks < 4)
                    ? *(const short8*)(As + (m * 16 + col16) * PAD2 + kh * 32 + quad * 8)
                    : *(const short8*)(commS + (m * 16 + col16) * CP + (k0 - 256) + kh * 32 + quad * 8);
        #pragma unroll
        for (int n = 0; n < 4; ++n)
            #pragma unroll
            for (int kh = 0; kh < 2; ++kh)
                bfr[n][kh] = *(const short8*)(Bs + (wave * 64 + n * 16 + col16) * PAD2 + kh * 32 + quad * 8);
        #pragma unroll
        for (int m = 0; m < 2; ++m)
            #pragma unroll
            for (int n = 0; n < 4; ++n)
                #pragma unroll
                for (int kh = 0; kh < 2; ++kh)
                    acc[m][n] = MFMA16(af[m][kh], bfr[n][kh], acc[m][n], 0, 0, 0);
        __syncthreads();
    }

    // epilogue A: bias + relu -> bf16 z tile in Ts (aliases Bs; safe after final barrier)
    #pragma unroll
    for (int m = 0; m < 2; ++m)
        #pragma unroll
        for (int n = 0; n < 4; ++n) {
            int gc = wave * 64 + n * 16 + col16;
            float bia = b1[gc];
            #pragma unroll
            for (int r = 0; r < 4; ++r) {
                int lr = m * 16 + quad * 4 + r;
                Ts[lr * TP + gc] = (short)f2bf(fmaxf(acc[m][n][r] + bia, 0.f));
            }
        }
    __syncthreads();

    // phase B2: out = z @ W2T^T + b2, K=256; wave owns cols [wave*16, wave*16+16)
    floatx4 acc2[2] = {};
    #pragma unroll
    for (int k0 = 0; k0 < DIM_H; k0 += 32) {
        short8 b = *(const short8*)(W2T + (size_t)(wave * 16 + col16) * DIM_H + k0 + quad * 8);
        #pragma unroll
        for (int m = 0; m < 2; ++m) {
            short8 a = *(const short8*)(Ts + (m * 16 + col16) * TP + k0 + quad * 8);
            acc2[m] = MFMA16(a, b, acc2[m], 0, 0, 0);
        }
    }
    #pragma unroll
    for (int m = 0; m < 2; ++m) {
        int gc = wave * 16 + col16;
        float bia = b2[gc];
        #pragma unroll
        for (int r = 0; r < 4; ++r) {
            int gr = row0 + m * 16 + quad * 4 + r;
            if (gr < M) out[(size_t)gr * DIM_OUT + gc] = acc2[m][r] + bia;
        }
    }
}

// ---------------- launcher: 4 dispatches ----------------
extern "C" void kernel_launch(void* const* d_in, const int* in_sizes, int n_in,
                              void* d_out, int out_size, void* d_ws, size_t ws_size,
                              hipStream_t stream) {
    (void)in_sizes; (void)n_in; (void)out_size; (void)ws_size;
    const float* x    = (const float*)d_in[0];
    const int*   ei   = (const int*)d_in[1];
    const float* W_in = (const float*)d_in[2];
    const float* b_in = (const float*)d_in[3];
    const float* Wq   = (const float*)d_in[4];
    const float* bq   = (const float*)d_in[5];
    const float* Wk   = (const float*)d_in[6];
    const float* bk   = (const float*)d_in[7];
    const float* Wv   = (const float*)d_in[8];
    const float* bv   = (const float*)d_in[9];
    const float* W1   = (const float*)d_in[10];
    const float* b1   = (const float*)d_in[11];
    const float* W2   = (const float*)d_in[12];
    const float* b2   = (const float*)d_in[13];
    float* out = (float*)d_out;

    uint32_t* ws      = (uint32_t*)d_ws;
    int*      deg     = (int*)(ws + OFF_DEG);
    int*      col     = (int*)(ws + OFF_COL);
    float*    qk      = (float*)(ws + OFF_QK);
    unsigned short* v_tab  = (unsigned short*)(ws + OFF_VT);
    unsigned short* cat_bf = (unsigned short*)(ws + OFF_CATBF);
    unsigned short* WinT   = (unsigned short*)(ws + OFF_WINT);
    unsigned short* WqkvT  = (unsigned short*)(ws + OFF_WQKVT);
    unsigned short* W1T    = (unsigned short*)(ws + OFF_W1T);
    unsigned short* W2T    = (unsigned short*)(ws + OFF_W2T);

    // 0) zero deg
    hipMemsetAsync(deg, 0, N_NODES * sizeof(int), stream);
    // 1) prep: weight transposes + edge bucket-scatter
    prep_w<<<512, 256, 0, stream>>>(W_in, Wq, Wk, Wv, ei, deg, col, WinT, WqkvT);
    // 2) fused h-GEMM + qkv-GEMM (+W1T/W2T tail), 313 blocks
    gemm12<<<(N_NODES + 31) / 32, 256, 0, stream>>>(
        x, WinT, b_in, WqkvT, bq, bk, bv, W1, W2, cat_bf, qk, v_tab, W1T, W2T);
    // 3) MERGED attention + W1/W2 (comm stays in LDS), 313 blocks
    attn_w1w2<<<(N_NODES + 31) / 32, 256, 0, stream>>>(
        qk, v_tab, deg, col, cat_bf, W1T, b1, W2T, b2, out, N_NODES);
}

// Round 13
// 159.246 us; speedup vs baseline: 1.3652x; 1.2176x over previous
//
#include <hip/hip_runtime.h>
#include <stdint.h>
#include <stddef.h>

// Problem constants (fixed by the reference).
constexpr int N_NODES = 10000;
constexpr int N_EDGES = 320000;
constexpr int DIM_IN  = 128;
constexpr int DIM_H   = 256;
constexpr int DIM_C   = 32;
constexpr int DIM_OUT = 64;
constexpr int DIM_QKV = DIM_C + DIM_C + DIM_H;  // 320 : [q|k|v]
constexpr int DIM_QK  = 2 * DIM_C;              // 64  : [q|k] compact fp32
constexpr int DIM_CAT = 2 * DIM_H;              // 512 : [h|comm]
constexpr float SCALE = 0.17677669529663687f;   // 1/sqrt(32)
constexpr float EXP2SC = 0.2550348612f;         // SCALE * log2(e)
constexpr int MAXD = 192;   // bucket capacity; Binomial(320k,1e-4) max ~66 (28 sigma margin)
constexpr float VSCALE = 64.0f;                 // fp8 v pre-scale (|v|max ~0.5 -> ~32 << 448)
constexpr int PAD2 = 72;    // 64-k LDS row stride (bf16): 144B rows, 16B-aligned (72=8*9)
constexpr int HP   = 264;   // h-tile LDS row stride: 528B rows, 16B-aligned

#if __has_builtin(__builtin_amdgcn_cvt_pk_f32_fp8) && __has_builtin(__builtin_amdgcn_cvt_pk_fp8_f32)
#define V_FP8 1
#else
#define V_FP8 0   // fallback: bf16 v
#endif

// ---------------- workspace layout (4-byte words) ----------------
constexpr size_t alignw(size_t w) { return (w + 15) & ~size_t(15); }
constexpr size_t OFF_DEG   = 0;
constexpr size_t OFF_COL   = alignw(OFF_DEG + N_NODES);                  // [N][MAXD] bucket
constexpr size_t OFF_QK    = alignw(OFF_COL + (size_t)N_NODES * MAXD);   // fp32 [N][64]
constexpr size_t OFF_VT    = alignw(OFF_QK + (size_t)N_NODES * DIM_QK);         // [N][256] fp8/bf16
constexpr size_t OFF_CATBF = alignw(OFF_VT + (size_t)N_NODES * DIM_H / 2);      // [N][512]
constexpr size_t OFF_WINT  = alignw(OFF_CATBF + (size_t)N_NODES * DIM_CAT / 2); // [256][128]
constexpr size_t OFF_WQKVT = alignw(OFF_WINT + (size_t)DIM_H * DIM_IN / 2);     // [320][256]
constexpr size_t OFF_W1T   = alignw(OFF_WQKVT + (size_t)DIM_QKV * DIM_H / 2);   // [256][512]
constexpr size_t OFF_W2T   = alignw(OFF_W1T + (size_t)DIM_H * DIM_CAT / 2);     // [64][256]

typedef __attribute__((ext_vector_type(8))) short short8;
typedef __attribute__((ext_vector_type(4))) float floatx4;
typedef __attribute__((ext_vector_type(2))) float floatx2;

#define MFMA16 __builtin_amdgcn_mfma_f32_16x16x32_bf16

__device__ inline unsigned short f2bf(float f) {
    uint32_t u = __builtin_bit_cast(uint32_t, f);
    uint32_t r = (u + 0x7fffu + ((u >> 16) & 1u)) >> 16;   // RNE
    return (unsigned short)r;
}
__device__ inline float bf2f_lo(uint32_t u) { return __builtin_bit_cast(float, u << 16); }
__device__ inline float bf2f_hi(uint32_t u) { return __builtin_bit_cast(float, u & 0xffff0000u); }

// ---------------- prep_w: deg zero + WinT/WqkvT transpose (R10-proven) ----------------
__global__ void prep_w(const float* __restrict__ W_in,
                       const float* __restrict__ Wq, const float* __restrict__ Wk,
                       const float* __restrict__ Wv,
                       int* __restrict__ deg,
                       unsigned short* __restrict__ WinT, unsigned short* __restrict__ WqkvT)
{
    const int i0 = blockIdx.x * blockDim.x + threadIdx.x;
    const int stride = gridDim.x * blockDim.x;
    for (int i = i0; i < N_NODES; i += stride) deg[i] = 0;
    for (int idx = i0; idx < DIM_IN * DIM_H; idx += stride) {    // W_in[128][256]
        int k = idx >> 8, n = idx & 255;
        WinT[n * DIM_IN + k] = f2bf(W_in[idx]);
    }
    for (int idx = i0; idx < DIM_H * DIM_C; idx += stride) {     // Wq[256][32] -> rows 0..31
        int k = idx >> 5, n = idx & 31;
        WqkvT[n * DIM_H + k] = f2bf(Wq[idx]);
    }
    for (int idx = i0; idx < DIM_H * DIM_C; idx += stride) {     // Wk -> rows 32..63
        int k = idx >> 5, n = idx & 31;
        WqkvT[(DIM_C + n) * DIM_H + k] = f2bf(Wk[idx]);
    }
    for (int idx = i0; idx < DIM_H * DIM_H; idx += stride) {     // Wv[256][256] -> rows 64..319
        int k = idx >> 8, n = idx & 255;
        WqkvT[(2 * DIM_C + n) * DIM_H + k] = f2bf(Wv[idx]);
    }
}

// ---------------- fused GEMM1+GEMM2, BM=32, K-step 64, REG-PREFETCH (R10-proven) ------
// Tail: edge bucket-scatter + W1T/W2T transpose (off MFMA critical path).
__global__ __launch_bounds__(256)
void gemm12(const float* __restrict__ x, const int* __restrict__ ei,
            const unsigned short* __restrict__ WinT, const float* __restrict__ b_in,
            const unsigned short* __restrict__ WqkvT,
            const float* __restrict__ bq, const float* __restrict__ bk,
            const float* __restrict__ bv,
            const float* __restrict__ W1, const float* __restrict__ W2,
            int* __restrict__ deg, int* __restrict__ col,
            unsigned short* __restrict__ cat_bf, float* __restrict__ qk,
            unsigned short* __restrict__ v_tab,
            unsigned short* __restrict__ W1T, unsigned short* __restrict__ W2T)
{
    __shared__ alignas(16) char SMEM[62976];
    short* hS  = (short*)SMEM;                    // 32 x 264 = 16,896 B
    short* As1 = (short*)(SMEM + 16896);          // 32 x 72  =  4,608 B (phase 1)
    short* Bs1 = (short*)(SMEM + 21504);          // 256 x 72 = 36,864 B (phase 1)
    short* Bs2 = (short*)(SMEM + 16896);          // 320 x 72 = 46,080 B (phase 2, overlaps)
    const int tid   = threadIdx.x;
    const int bid   = blockIdx.x;
    const int wave  = tid >> 6;
    const int lane  = tid & 63;
    const int quad  = lane >> 4;
    const int col16 = lane & 15;
    const int sr    = tid >> 3;          // staging row 0..31
    const int sc    = (tid & 7) * 8;     // staging k-chunk (8 bf16 = 16B), 0..56
    const int row0  = bid * 32;
    const int gr_s  = row0 + sr;

    // ---- phase-1 prologue: issue k0=0 tile loads ----
    float4 xa = {}, xb = {};
    if (gr_s < N_NODES) {
        const float4* xp = (const float4*)(x + (size_t)gr_s * DIM_IN + sc);
        xa = xp[0]; xb = xp[1];
    }
    short8 wreg[8];
    #pragma unroll
    for (int p = 0; p < 8; ++p)
        wreg[p] = *(const short8*)(WinT + (size_t)(sr + p * 32) * DIM_IN + sc);

    short8 breg[10];   // phase-2 prefetch registers
    floatx4 acc[2][4] = {};
    #pragma unroll
    for (int k0 = 0; k0 < DIM_IN; k0 += 64) {
        {   // ds_write staged x tile (inline f32->bf16)
            uint4 o;
            o.x = (uint32_t)f2bf(xa.x) | ((uint32_t)f2bf(xa.y) << 16);
            o.y = (uint32_t)f2bf(xa.z) | ((uint32_t)f2bf(xa.w) << 16);
            o.z = (uint32_t)f2bf(xb.x) | ((uint32_t)f2bf(xb.y) << 16);
            o.w = (uint32_t)f2bf(xb.z) | ((uint32_t)f2bf(xb.w) << 16);
            *(uint4*)(As1 + sr * PAD2 + sc) = o;
        }
        #pragma unroll
        for (int p = 0; p < 8; ++p)
            *(short8*)(Bs1 + (sr + p * 32) * PAD2 + sc) = wreg[p];
        if (k0 + 64 < DIM_IN) {
            xa = {}; xb = {};
            if (gr_s < N_NODES) {
                const float4* xp = (const float4*)(x + (size_t)gr_s * DIM_IN + (k0 + 64) + sc);
                xa = xp[0]; xb = xp[1];
            }
            #pragma unroll
            for (int p = 0; p < 8; ++p)
                wreg[p] = *(const short8*)(WinT + (size_t)(sr + p * 32) * DIM_IN + (k0 + 64) + sc);
        } else {
            #pragma unroll
            for (int p = 0; p < 10; ++p)
                breg[p] = *(const short8*)(WqkvT + (size_t)(sr + p * 32) * DIM_H + sc);
        }
        __syncthreads();
        short8 af[2][2], bfr[4][2];
        #pragma unroll
        for (int m = 0; m < 2; ++m)
            #pragma unroll
            for (int kh = 0; kh < 2; ++kh)
                af[m][kh] = *(const short8*)(As1 + (m * 16 + col16) * PAD2 + kh * 32 + quad * 8);
        #pragma unroll
        for (int n = 0; n < 4; ++n)
            #pragma unroll
            for (int kh = 0; kh < 2; ++kh)
                bfr[n][kh] = *(const short8*)(Bs1 + (wave * 64 + n * 16 + col16) * PAD2 + kh * 32 + quad * 8);
        #pragma unroll
        for (int m = 0; m < 2; ++m)
            #pragma unroll
            for (int n = 0; n < 4; ++n)
                #pragma unroll
                for (int kh = 0; kh < 2; ++kh)
                    acc[m][n] = MFMA16(af[m][kh], bfr[n][kh], acc[m][n], 0, 0, 0);
        __syncthreads();
    }
    // epilogue 1: bias -> bf16 -> hS (LDS) + cat_bf[:, 0:256] (global, for w1w2)
    #pragma unroll
    for (int m = 0; m < 2; ++m)
        #pragma unroll
        for (int n = 0; n < 4; ++n) {
            int gc = wave * 64 + n * 16 + col16;
            float bia = b_in[gc];
            #pragma unroll
            for (int r = 0; r < 4; ++r) {
                int lr = m * 16 + quad * 4 + r;
                unsigned short hv = f2bf(acc[m][n][r] + bia);
                hS[lr * HP + gc] = (short)hv;
                if (row0 + lr < N_NODES) cat_bf[(size_t)(row0 + lr) * DIM_CAT + gc] = hv;
            }
        }
    __syncthreads();

    // ---- phase 2: qkv = h @ WqkvT^T + bias  (K=256, 4 k-steps of 64, prefetched) ----
    floatx4 acc2[2][5] = {};
    #pragma unroll
    for (int k0 = 0; k0 < DIM_H; k0 += 64) {
        #pragma unroll
        for (int p = 0; p < 10; ++p)
            *(short8*)(Bs2 + (sr + p * 32) * PAD2 + sc) = breg[p];
        if (k0 + 64 < DIM_H) {
            #pragma unroll
            for (int p = 0; p < 10; ++p)
                breg[p] = *(const short8*)(WqkvT + (size_t)(sr + p * 32) * DIM_H + (k0 + 64) + sc);
        }
        __syncthreads();
        short8 af[2][2], bfr[5][2];
        #pragma unroll
        for (int m = 0; m < 2; ++m)
            #pragma unroll
            for (int kh = 0; kh < 2; ++kh)
                af[m][kh] = *(const short8*)(hS + (m * 16 + col16) * HP + k0 + kh * 32 + quad * 8);
        #pragma unroll
        for (int n = 0; n < 5; ++n)
            #pragma unroll
            for (int kh = 0; kh < 2; ++kh)
                bfr[n][kh] = *(const short8*)(Bs2 + (wave * 80 + n * 16 + col16) * PAD2 + kh * 32 + quad * 8);
        #pragma unroll
        for (int m = 0; m < 2; ++m)
            #pragma unroll
            for (int n = 0; n < 5; ++n)
                #pragma unroll
                for (int kh = 0; kh < 2; ++kh)
                    acc2[m][n] = MFMA16(af[m][kh], bfr[n][kh], acc2[m][n], 0, 0, 0);
        __syncthreads();
    }
    // epilogue 2: split -> qk fp32 [N][64], v fp8/bf16 [N][256]; bias read direct
    #pragma unroll
    for (int m = 0; m < 2; ++m)
        #pragma unroll
        for (int n = 0; n < 5; ++n) {
            int gc = wave * 80 + n * 16 + col16;
            float bia = (gc < DIM_C) ? bq[gc] : (gc < DIM_QK) ? bk[gc - DIM_C] : bv[gc - DIM_QK];
            #pragma unroll
            for (int r = 0; r < 4; ++r) {
                int gr = row0 + m * 16 + quad * 4 + r;
                if (gr >= N_NODES) continue;
                float v = acc2[m][n][r] + bia;
                if (gc < DIM_QK) {
                    qk[(size_t)gr * DIM_QK + gc] = v;
                } else {
#if V_FP8
                    int pk = __builtin_amdgcn_cvt_pk_fp8_f32(v * VSCALE, 0.f, 0, false);
                    ((unsigned char*)v_tab)[(size_t)gr * DIM_H + (gc - DIM_QK)] =
                        (unsigned char)(pk & 0xff);
#else
                    v_tab[(size_t)gr * DIM_H + (gc - DIM_QK)] = f2bf(v);
#endif
                }
            }
        }

    // ---- tail (off critical path): edge bucket-scatter + W1T/W2T transpose ----
    {
        const int stride = gridDim.x * 256;              // 80,128
        const int i0 = bid * 256 + tid;
        int s4[4], d4[4]; bool ok[4];
        #pragma unroll
        for (int t = 0; t < 4; ++t) {
            int e = i0 + t * stride;
            ok[t] = e < N_EDGES;
            s4[t] = ok[t] ? ei[e] : 0;
            d4[t] = ok[t] ? ei[N_EDGES + e] : 0;
        }
        #pragma unroll
        for (int t = 0; t < 4; ++t)
            if (ok[t]) {
                int slot = atomicAdd(&deg[s4[t]], 1);
                if (slot < MAXD) col[s4[t] * MAXD + slot] = d4[t];
            }
        for (int idx = i0; idx < DIM_CAT * DIM_H; idx += stride) {   // W1[512][256]
            int k = idx >> 8, n = idx & 255;
            W1T[n * DIM_CAT + k] = f2bf(W1[idx]);
        }
        for (int idx = i0; idx < DIM_H * DIM_OUT; idx += stride) {   // W2[256][64]
            int k = idx >> 6, n = idx & 63;
            W2T[n * DIM_H + k] = f2bf(W2[idx]);
        }
    }
}

// ---------------- fused per-row attention: PAIR-GATHER (R10-proven) -------------------
// One wave per row, 4 rows per block (2500 blocks = 39 waves/CU TLP — keep WIDE).
__global__ __launch_bounds__(256)
void attn_row(const float* __restrict__ qk, const unsigned short* __restrict__ v_tab,
              const int* __restrict__ deg, const int* __restrict__ col,
              unsigned short* __restrict__ cat_bf) {
    __shared__ alignas(16) int dstS[4][MAXD];
    __shared__ float wS[4][MAXD];
    __shared__ float qS[4][DIM_C];
    const int wave = threadIdx.x >> 6;
    const int lane = threadIdx.x & 63;
    const int row = blockIdx.x * 4 + wave;   // grid is exactly N_NODES/4
    int d = deg[row];
    if (d > MAXD) d = MAXD;
    const int* crow = col + (size_t)row * MAXD;

    for (int p = lane; p < d; p += 64) dstS[wave][p] = crow[p];
    if (lane < DIM_C) qS[wave][lane] = qk[(size_t)row * DIM_QK + lane];
    __syncthreads();

    float mysum = 0.f;
    if (d <= 64) {
        int mydst = (lane < d) ? dstS[wave][lane] : -1;
        bool dup = false;
        {
            const int4* ds4 = (const int4*)(&dstS[wave][0]);
            const int lim = (lane < d) ? lane : 0;
            for (int j0 = 0; j0 < lim; j0 += 4) {
                int4 v = ds4[j0 >> 2];
                dup = dup || (v.x == mydst)
                   || (j0 + 1 < lim && v.y == mydst)
                   || (j0 + 2 < lim && v.z == mydst)
                   || (j0 + 3 < lim && v.w == mydst);
            }
        }
        float w = 0.f;
        if (lane < d && !dup) {
            const float4* kp = (const float4*)(qk + (size_t)mydst * DIM_QK + DIM_C);
            float s = 0.f;
            #pragma unroll
            for (int i = 0; i < DIM_C / 4; ++i) {
                float4 b = kp[i];
                s += qS[wave][4 * i + 0] * b.x + qS[wave][4 * i + 1] * b.y
                   + qS[wave][4 * i + 2] * b.z + qS[wave][4 * i + 3] * b.w;
            }
            w = exp2f(s * EXP2SC);
        }
        wS[wave][lane] = w;
        mysum = w;
    } else {
        for (int p = lane; p < d; p += 64) {
            int mydst = dstS[wave][p];
            bool dup = false;
            for (int j = 0; j < p; ++j) dup = dup || (dstS[wave][j] == mydst);
            float w = 0.f;
            if (!dup) {
                const float4* kp = (const float4*)(qk + (size_t)mydst * DIM_QK + DIM_C);
                float s = 0.f;
                #pragma unroll
                for (int i = 0; i < DIM_C / 4; ++i) {
                    float4 b = kp[i];
                    s += qS[wave][4 * i + 0] * b.x + qS[wave][4 * i + 1] * b.y
                       + qS[wave][4 * i + 2] * b.z + qS[wave][4 * i + 3] * b.w;
                }
                w = exp2f(s * EXP2SC);
            }
            wS[wave][p] = w;
            mysum += w;
        }
    }
    #pragma unroll
    for (int off = 32; off; off >>= 1) mysum += __shfl_down(mysum, off, 64);
    float total = __shfl(mysum, 0, 64);
#if V_FP8
    float inv = (d > 0 && total > 0.f) ? 1.0f / (total * VSCALE) : 0.f;
#else
    float inv = (d > 0 && total > 0.f) ? 1.0f / total : 0.f;
#endif
    __syncthreads();

    // pair-gather: half h handles neighbors p0+2t+h; lane covers cols [l32*8, l32*8+8)
    const int half = lane >> 5;
    const int l32  = lane & 31;
    float a8[8] = {};
#if V_FP8
    const uint2* vb2 = (const uint2*)v_tab;          // fp8 row = 32 uint2 (256 B)
    for (int p0 = 0; p0 < d; p0 += 16) {
        int j[8]; float w[8];
        #pragma unroll
        for (int t = 0; t < 8; ++t) {
            int idx = p0 + 2 * t + half;
            bool in = idx < d;
            j[t] = in ? dstS[wave][idx] : 0;         // pad: row 0 (L2-hot), weight 0
            w[t] = in ? wS[wave][idx] : 0.f;
        }
        uint2 r[8];
        #pragma unroll
        for (int t = 0; t < 8; ++t) r[t] = vb2[(size_t)j[t] * 32 + l32];
        #pragma unroll
        for (int t = 0; t < 8; ++t) {
            floatx2 c0 = __builtin_amdgcn_cvt_pk_f32_fp8(r[t].x, false);
            floatx2 c1 = __builtin_amdgcn_cvt_pk_f32_fp8(r[t].x, true);
            floatx2 c2 = __builtin_amdgcn_cvt_pk_f32_fp8(r[t].y, false);
            floatx2 c3 = __builtin_amdgcn_cvt_pk_f32_fp8(r[t].y, true);
            a8[0] += w[t] * c0.x; a8[1] += w[t] * c0.y;
            a8[2] += w[t] * c1.x; a8[3] += w[t] * c1.y;
            a8[4] += w[t] * c2.x; a8[5] += w[t] * c2.y;
            a8[6] += w[t] * c3.x; a8[7] += w[t] * c3.y;
        }
    }
#else
    const uint4* vb2 = (const uint4*)v_tab;          // bf16 row = 32 uint4 (512 B)
    for (int p0 = 0; p0 < d; p0 += 16) {
        int j[8]; float w[8];
        #pragma unroll
        for (int t = 0; t < 8; ++t) {
            int idx = p0 + 2 * t + half;
            bool in = idx < d;
            j[t] = in ? dstS[wave][idx] : 0;
            w[t] = in ? wS[wave][idx] : 0.f;
        }
        uint4 r[8];
        #pragma unroll
        for (int t = 0; t < 8; ++t) r[t] = vb2[(size_t)j[t] * 32 + l32];
        #pragma unroll
        for (int t = 0; t < 8; ++t) {
            a8[0] += w[t] * bf2f_lo(r[t].x); a8[1] += w[t] * bf2f_hi(r[t].x);
            a8[2] += w[t] * bf2f_lo(r[t].y); a8[3] += w[t] * bf2f_hi(r[t].y);
            a8[4] += w[t] * bf2f_lo(r[t].z); a8[5] += w[t] * bf2f_hi(r[t].z);
            a8[6] += w[t] * bf2f_lo(r[t].w); a8[7] += w[t] * bf2f_hi(r[t].w);
        }
    }
#endif
    #pragma unroll
    for (int i = 0; i < 8; ++i) {
        a8[i] += __shfl_xor(a8[i], 32, 64);
        a8[i] *= inv;
    }
    if (half == 0) {
        uint4 o;
        o.x = (uint32_t)f2bf(a8[0]) | ((uint32_t)f2bf(a8[1]) << 16);
        o.y = (uint32_t)f2bf(a8[2]) | ((uint32_t)f2bf(a8[3]) << 16);
        o.z = (uint32_t)f2bf(a8[4]) | ((uint32_t)f2bf(a8[5]) << 16);
        o.w = (uint32_t)f2bf(a8[6]) | ((uint32_t)f2bf(a8[7]) << 16);
        *(uint4*)(cat_bf + (size_t)row * DIM_CAT + DIM_H + l32 * 8) = o;
    }
}

// ---------------- fused W1(relu) + W2 GEMM, BM=32, K-step 64, REG-PREFETCH (R10) ------
__global__ __launch_bounds__(256)
void gemm_w1w2(const unsigned short* __restrict__ cat, const unsigned short* __restrict__ W1T,
               const float* __restrict__ b1, const unsigned short* __restrict__ W2T,
               const float* __restrict__ b2, float* __restrict__ out, int M)
{
    constexpr int TP = 260;   // Ts row stride (bf16)
    __shared__ short As[32 * PAD2];                //  4,608 B
    __shared__ short BsTs[256 * PAD2];             // 36,864 B: Bs; Ts (32*260*2=16,640) aliases
    short* Bs = BsTs;
    short* Ts = BsTs;
    const int tid   = threadIdx.x;
    const int wave  = tid >> 6;
    const int lane  = tid & 63;
    const int quad  = lane >> 4;
    const int col16 = lane & 15;
    const int row0  = blockIdx.x * 32;

    const int sr = tid >> 3;          // 0..31
    const int sc = (tid & 7) * 8;     // 16B k-chunk, 0..56
    const int gr_s = row0 + sr;

    // prologue: issue k0=0 tile loads
    short8 areg = {};
    if (gr_s < M) areg = *(const short8*)(cat + (size_t)gr_s * DIM_CAT + sc);
    short8 breg[8];
    #pragma unroll
    for (int p = 0; p < 8; ++p)
        breg[p] = *(const short8*)(W1T + (size_t)(sr + p * 32) * DIM_CAT + sc);

    // ---- phase A: z = relu(cat @ W1T^T + b1), 32 rows x 256 cols, K=512 (8 steps) ----
    floatx4 acc[2][4] = {};
    #pragma unroll
    for (int k0 = 0; k0 < DIM_CAT; k0 += 64) {
        *(short8*)(As + sr * PAD2 + sc) = areg;
        #pragma unroll
        for (int p = 0; p < 8; ++p)
            *(short8*)(Bs + (sr + p * 32) * PAD2 + sc) = breg[p];
        if (k0 + 64 < DIM_CAT) {   // prefetch next tile (hidden under MFMA below)
            areg = short8{};
            if (gr_s < M) areg = *(const short8*)(cat + (size_t)gr_s * DIM_CAT + (k0 + 64) + sc);
            #pragma unroll
            for (int p = 0; p < 8; ++p)
                breg[p] = *(const short8*)(W1T + (size_t)(sr + p * 32) * DIM_CAT + (k0 + 64) + sc);
        }
        __syncthreads();
        short8 af[2][2], bfr[4][2];
        #pragma unroll
        for (int m = 0; m < 2; ++m)
            #pragma unroll
            for (int kh = 0; kh < 2; ++kh)
                af[m][kh] = *(const short8*)(As + (m * 16 + col16) * PAD2 + kh * 32 + quad * 8);
        #pragma unroll
        for (int n = 0; n < 4; ++n)
            #pragma unroll
            for (int kh = 0; kh < 2; ++kh)
                bfr[n][kh] = *(const short8*)(Bs + (wave * 64 + n * 16 + col16) * PAD2 + kh * 32 + quad * 8);
        #pragma unroll
        for (int m = 0; m < 2; ++m)
            #pragma unroll
            for (int n = 0; n < 4; ++n)
                #pragma unroll
                for (int kh = 0; kh < 2; ++kh)
                    acc[m][n] = MFMA16(af[m][kh], bfr[n][kh], acc[m][n], 0, 0, 0);
        __syncthreads();   // Bs reads done before next staging / Ts overwrite
    }

    // epilogue A: bias + relu -> bf16 z tile in Ts (aliases Bs; safe after final barrier)
    #pragma unroll
    for (int m = 0; m < 2; ++m)
        #pragma unroll
        for (int n = 0; n < 4; ++n) {
            int gc = wave * 64 + n * 16 + col16;
            float bia = b1[gc];
            #pragma unroll
            for (int r = 0; r < 4; ++r) {
                int lr = m * 16 + quad * 4 + r;
                Ts[lr * TP + gc] = (short)f2bf(fmaxf(acc[m][n][r] + bia, 0.f));
            }
        }
    __syncthreads();

    // ---- phase B: out = z @ W2T^T + b2, K=256; wave owns cols [wave*16, wave*16+16) ----
    floatx4 acc2[2] = {};
    #pragma unroll
    for (int k0 = 0; k0 < DIM_H; k0 += 32) {
        short8 b = *(const short8*)(W2T + (size_t)(wave * 16 + col16) * DIM_H + k0 + quad * 8);
        #pragma unroll
        for (int m = 0; m < 2; ++m) {
            short8 a = *(const short8*)(Ts + (m * 16 + col16) * TP + k0 + quad * 8);
            acc2[m] = MFMA16(a, b, acc2[m], 0, 0, 0);
        }
    }
    #pragma unroll
    for (int m = 0; m < 2; ++m) {
        int gc = wave * 16 + col16;
        float bia = b2[gc];
        #pragma unroll
        for (int r = 0; r < 4; ++r) {
            int gr = row0 + m * 16 + quad * 4 + r;
            if (gr < M) out[(size_t)gr * DIM_OUT + gc] = acc2[m][r] + bia;
        }
    }
}

// ---------------- launcher: 4 dispatches (best-known split structure) ----------------
extern "C" void kernel_launch(void* const* d_in, const int* in_sizes, int n_in,
                              void* d_out, int out_size, void* d_ws, size_t ws_size,
                              hipStream_t stream) {
    (void)in_sizes; (void)n_in; (void)out_size; (void)ws_size;
    const float* x    = (const float*)d_in[0];
    const int*   ei   = (const int*)d_in[1];
    const float* W_in = (const float*)d_in[2];
    const float* b_in = (const float*)d_in[3];
    const float* Wq   = (const float*)d_in[4];
    const float* bq   = (const float*)d_in[5];
    const float* Wk   = (const float*)d_in[6];
    const float* bk   = (const float*)d_in[7];
    const float* Wv   = (const float*)d_in[8];
    const float* bv   = (const float*)d_in[9];
    const float* W1   = (const float*)d_in[10];
    const float* b1   = (const float*)d_in[11];
    const float* W2   = (const float*)d_in[12];
    const float* b2   = (const float*)d_in[13];
    float* out = (float*)d_out;

    uint32_t* ws      = (uint32_t*)d_ws;
    int*      deg     = (int*)(ws + OFF_DEG);
    int*      col     = (int*)(ws + OFF_COL);
    float*    qk      = (float*)(ws + OFF_QK);
    unsigned short* v_tab  = (unsigned short*)(ws + OFF_VT);
    unsigned short* cat_bf = (unsigned short*)(ws + OFF_CATBF);
    unsigned short* WinT   = (unsigned short*)(ws + OFF_WINT);
    unsigned short* WqkvT  = (unsigned short*)(ws + OFF_WQKVT);
    unsigned short* W1T    = (unsigned short*)(ws + OFF_W1T);
    unsigned short* W2T    = (unsigned short*)(ws + OFF_W2T);

    // 1) minimal blocking prep: deg zero + WinT/WqkvT transpose
    prep_w<<<256, 256, 0, stream>>>(W_in, Wq, Wk, Wv, deg, WinT, WqkvT);
    // 2) fused h-GEMM + qkv-GEMM, reg-prefetch (+scatter/W1T/W2T tail), 313 blocks
    gemm12<<<(N_NODES + 31) / 32, 256, 0, stream>>>(
        x, ei, WinT, b_in, WqkvT, bq, bk, bv, W1, W2,
        deg, col, cat_bf, qk, v_tab, W1T, W2T);
    // 3) fused sparse attention (pair-gather, exp2), 2500 blocks — wide TLP
    attn_row<<<N_NODES / 4, 256, 0, stream>>>(qk, v_tab, deg, col, cat_bf);
    // 4) out = relu(cat@W1+b1)@W2 + b2, 313 blocks
    gemm_w1w2<<<(N_NODES + 31) / 32, 256, 0, stream>>>(
        cat_bf, W1T, b1, W2T, b2, out, N_NODES);
}